// Round 2
// baseline (807.825 us; speedup 1.0000x reference)
//
#include <hip/hip_runtime.h>

namespace {
constexpr int Hh = 128, Ww = 128, HW = Hh * Ww;
constexpr int Bn = 4;
constexpr int Cc = 64;

constexpr int N_WT1 = 9 * 64 * 64;   // 36864  wt1[(k*64+c)*64+o]
constexpr int N_WT2 = 9 * 64 * 32;   // 18432  wt2[(k*64+c)*32+o]
constexpr int N_WTO = 64 * 9 * 27;   // 15552  wto[(c*9+k)*27+o]
constexpr int N_BN  = 192;

__global__ __launch_bounds__(256)
void prep_kernel(const float* __restrict__ w1, const float* __restrict__ w2,
                 const float* __restrict__ wo1, const float* __restrict__ wo2,
                 const float* __restrict__ g1, const float* __restrict__ be1,
                 const float* __restrict__ rm1, const float* __restrict__ rv1,
                 const float* __restrict__ g2, const float* __restrict__ be2,
                 const float* __restrict__ rm2, const float* __restrict__ rv2,
                 float* __restrict__ wt1, float* __restrict__ wt2,
                 float* __restrict__ wto1, float* __restrict__ wto2,
                 float* __restrict__ bn)
{
  int i = blockIdx.x * 256 + threadIdx.x;
  if (i < N_WT1) {
    int o = i & 63, c = (i >> 6) & 63, k = i >> 12;
    wt1[i] = w1[(o * 64 + c) * 9 + k];
  } else if (i < N_WT1 + N_WT2) {
    int j = i - N_WT1;
    int o = j & 31, c = (j >> 5) & 63, k = j >> 11;
    wt2[j] = w2[(o * 64 + c) * 9 + k];
  } else if (i < N_WT1 + N_WT2 + N_WTO) {
    int j = i - (N_WT1 + N_WT2);
    int o = j % 27, r = j / 27;
    int k = r % 9, c = r / 9;
    wto1[j] = wo1[(o * 64 + c) * 9 + k];
  } else if (i < N_WT1 + N_WT2 + 2 * N_WTO) {
    int j = i - (N_WT1 + N_WT2 + N_WTO);
    int o = j % 27, r = j / 27;
    int k = r % 9, c = r / 9;
    wto2[j] = wo2[(o * 64 + c) * 9 + k];
  } else if (i < N_WT1 + N_WT2 + 2 * N_WTO + N_BN) {
    int j = i - (N_WT1 + N_WT2 + 2 * N_WTO);
    if (j < 64)       { float inv = g1[j] * rsqrtf(rv1[j] + 1e-5f); bn[j] = inv; }
    else if (j < 128) { int c = j - 64;  float inv = g1[c] * rsqrtf(rv1[c] + 1e-5f); bn[j] = be1[c] - rm1[c] * inv; }
    else if (j < 160) { int c = j - 128; float inv = g2[c] * rsqrtf(rv2[c] + 1e-5f); bn[j] = inv; }
    else              { int c = j - 160; float inv = g2[c] * rsqrtf(rv2[c] + 1e-5f); bn[j] = be2[c] - rm2[c] * inv; }
  }
}

// 3x3 conv, 64 -> 27 channels, pad 1. One thread per output pixel, 27 accumulators.
// Weight reads are wave-uniform (loop-counter indexed) -> scalar loads.
template<bool VIRT>
__global__ __launch_bounds__(256)
void conv27_kernel(const float* __restrict__ xin,
                   const float* __restrict__ pA, const float* __restrict__ pB,
                   const float* __restrict__ wt,    // [(c*9+k)*27+o]
                   const float* __restrict__ bias,  // 27
                   float* __restrict__ off)         // (B,27,H,W)
{
  int p = blockIdx.x * 256 + threadIdx.x;
  int b = p >> 14, hw = p & (HW - 1);
  int h = hw >> 7, w = hw & (Ww - 1);
  float acc[27];
  #pragma unroll
  for (int o = 0; o < 27; o++) acc[o] = bias[o];
  const float* baseA = pA + b * 32 * HW;
  const float* baseB = pB + b * 32 * HW;
  const float* baseX = xin + b * 64 * HW;
  for (int c = 0; c < Cc; c++) {
    const float* plane = VIRT ? (c < 32 ? baseB + c * HW : baseA + (c - 32) * HW)
                              : baseX + c * HW;
    float xv[9];
    #pragma unroll
    for (int ty = 0; ty < 3; ty++) {
      int yy = h + ty - 1;
      #pragma unroll
      for (int tx = 0; tx < 3; tx++) {
        int xx = w + tx - 1;
        bool ok = ((unsigned)yy < (unsigned)Hh) && ((unsigned)xx < (unsigned)Ww);
        xv[ty * 3 + tx] = ok ? plane[yy * Ww + xx] : 0.f;
      }
    }
    const float* wr = wt + c * 9 * 27;
    #pragma unroll
    for (int k = 0; k < 9; k++) {
      float xk = xv[k];
      #pragma unroll
      for (int o = 0; o < 27; o++) acc[o] = fmaf(wr[k * 27 + o], xk, acc[o]);
    }
  }
  float* op = off + b * 27 * HW + hw;
  #pragma unroll
  for (int o = 0; o < 27; o++) op[o * HW] = acc[o];
}

// Modulated deformable conv + BN + ReLU (+ optional final attention mask).
// One thread per pixel; O accumulators; per (k): bilinear setup folded with
// sigmoid(mask); per (k,c): 4 gathers + O FMAs with wave-uniform weights.
template<bool VIRT, int O, bool FINAL>
__global__ __launch_bounds__(256)
void deform_kernel(const float* __restrict__ xin,
                   const float* __restrict__ pA, const float* __restrict__ pB,
                   const float* __restrict__ off,   // (B,27,H,W)
                   const float* __restrict__ wt,    // [(k*64+c)*O+o]
                   const float* __restrict__ scale, const float* __restrict__ shift,
                   const float* __restrict__ Aatt, const float* __restrict__ Batt,
                   float* __restrict__ out)         // (B,O,H,W)
{
  int p = blockIdx.x * 256 + threadIdx.x;
  int b = p >> 14, hw = p & (HW - 1);
  int h = hw >> 7, w = hw & (Ww - 1);
  const float* offb = off + b * 27 * HW + hw;
  const float* baseA = pA + b * 32 * HW;
  const float* baseB = pB + b * 32 * HW;
  const float* baseX = xin + b * 64 * HW;
  float acc[O];
  #pragma unroll
  for (int o = 0; o < O; o++) acc[o] = 0.f;

  for (int k = 0; k < 9; k++) {
    float dy = offb[(2 * k) * HW];
    float dx = offb[(2 * k + 1) * HW];
    float mm = offb[(18 + k) * HW];
    float m = 1.f / (1.f + __expf(-mm));
    float ys = (float)(h + k / 3 - 1) + dy;
    float xs = (float)(w + k % 3 - 1) + dx;
    float y0f = floorf(ys), x0f = floorf(xs);
    float fy = ys - y0f, fx = xs - x0f;
    int y0 = (int)y0f, x0 = (int)x0f;
    int y1 = y0 + 1, x1 = x0 + 1;
    float vy0 = ((unsigned)y0 < (unsigned)Hh) ? 1.f : 0.f;
    float vy1 = ((unsigned)y1 < (unsigned)Hh) ? 1.f : 0.f;
    float vx0 = ((unsigned)x0 < (unsigned)Ww) ? 1.f : 0.f;
    float vx1 = ((unsigned)x1 < (unsigned)Ww) ? 1.f : 0.f;
    int cy0 = min(max(y0, 0), Hh - 1), cy1 = min(max(y1, 0), Hh - 1);
    int cx0 = min(max(x0, 0), Ww - 1), cx1 = min(max(x1, 0), Ww - 1);
    int i00 = cy0 * Ww + cx0, i01 = cy0 * Ww + cx1;
    int i10 = cy1 * Ww + cx0, i11 = cy1 * Ww + cx1;
    float w00 = (1.f - fy) * (1.f - fx) * m * vy0 * vx0;
    float w01 = (1.f - fy) * fx * m * vy0 * vx1;
    float w10 = fy * (1.f - fx) * m * vy1 * vx0;
    float w11 = fy * fx * m * vy1 * vx1;
    const float* wk = wt + k * 64 * O;
    for (int c = 0; c < Cc; c++) {
      const float* plane = VIRT ? (c < 32 ? baseB + c * HW : baseA + (c - 32) * HW)
                                : baseX + c * HW;
      float s = w00 * plane[i00] + w01 * plane[i01] + w10 * plane[i10] + w11 * plane[i11];
      const float* wr = wk + c * O;
      #pragma unroll
      for (int o = 0; o < O; o++) acc[o] = fmaf(wr[o], s, acc[o]);
    }
  }

  float fmul = 1.f;
  if (FINAL) {
    float a = Aatt[b * HW + hw], bb = Batt[b * HW + hw];
    fmul = (1.f - a) * bb;
  }
  float* op = out + b * O * HW + hw;
  #pragma unroll
  for (int o = 0; o < O; o++) {
    float v = fmaf(acc[o], scale[o], shift[o]);
    v = v > 0.f ? v : 0.f;
    op[o * HW] = FINAL ? v * fmul : v;
  }
}

} // namespace

extern "C" void kernel_launch(void* const* d_in, const int* in_sizes, int n_in,
                              void* d_out, int out_size, void* d_ws, size_t ws_size,
                              hipStream_t stream) {
  // setup_inputs order: p_fea(0, unused), pA(1), pB(2), A_att(3), B_att(4),
  // w_off1(5), b_off1(6), w1(7), g1(8), be1(9), rm1(10), rv1(11),
  // w_off2(12), b_off2(13), w2(14), g2(15), be2(16), rm2(17), rv2(18)
  const float* pA   = (const float*)d_in[1];
  const float* pB   = (const float*)d_in[2];
  const float* Aatt = (const float*)d_in[3];
  const float* Batt = (const float*)d_in[4];
  const float* wo1  = (const float*)d_in[5];
  const float* bo1  = (const float*)d_in[6];
  const float* w1   = (const float*)d_in[7];
  const float* g1   = (const float*)d_in[8];
  const float* be1  = (const float*)d_in[9];
  const float* rm1  = (const float*)d_in[10];
  const float* rv1  = (const float*)d_in[11];
  const float* wo2  = (const float*)d_in[12];
  const float* bo2  = (const float*)d_in[13];
  const float* w2   = (const float*)d_in[14];
  const float* g2   = (const float*)d_in[15];
  const float* be2  = (const float*)d_in[16];
  const float* rm2  = (const float*)d_in[17];
  const float* rv2  = (const float*)d_in[18];

  float* ws   = (float*)d_ws;
  float* off  = ws;                       // 4*27*16384 = 1769472 floats
  float* out1 = off + Bn * 27 * HW;       // 4*64*16384 = 4194304 floats
  float* wt1  = out1 + Bn * 64 * HW;
  float* wt2  = wt1 + N_WT1;
  float* wto1 = wt2 + N_WT2;
  float* wto2 = wto1 + N_WTO;
  float* bn   = wto2 + N_WTO;             // 192 floats
  float* sc1 = bn, * sh1 = bn + 64, * sc2 = bn + 128, * sh2 = bn + 160;

  int prep_n = N_WT1 + N_WT2 + 2 * N_WTO + N_BN;
  prep_kernel<<<(prep_n + 255) / 256, 256, 0, stream>>>(
      w1, w2, wo1, wo2, g1, be1, rm1, rv1, g2, be2, rm2, rv2,
      wt1, wt2, wto1, wto2, bn);

  // stage 1: virtual concat(pB, pA) as input
  conv27_kernel<true><<<256, 256, 0, stream>>>(pA, pA, pB, wto1, bo1, off);
  deform_kernel<true, 64, false><<<256, 256, 0, stream>>>(
      pA, pA, pB, off, wt1, sc1, sh1, nullptr, nullptr, out1);

  // stage 2: out1 as input
  conv27_kernel<false><<<256, 256, 0, stream>>>(out1, pA, pB, wto2, bo2, off);
  deform_kernel<false, 32, true><<<256, 256, 0, stream>>>(
      out1, pA, pB, off, wt2, sc2, sh2, Aatt, Batt, (float*)d_out);
}

// Round 3
// 806.147 us; speedup vs baseline: 1.0021x; 1.0021x over previous
//
#include <hip/hip_runtime.h>

namespace {
constexpr int Hh = 128, Ww = 128, HW = Hh * Ww;
constexpr int Bn = 4;
constexpr int Cc = 64;

constexpr int N_WT1 = 9 * 64 * 64;   // wt1[(k*64+c)*64+o]
constexpr int N_WT2 = 9 * 64 * 32;   // wt2[(k*64+c)*32+o]
constexpr int N_WTO = 64 * 9 * 27;   // wto[(c*9+k)*27+o]
constexpr int N_BN  = 192;

__global__ __launch_bounds__(256)
void prep_kernel(const float* __restrict__ w1, const float* __restrict__ w2,
                 const float* __restrict__ wo1, const float* __restrict__ wo2,
                 const float* __restrict__ g1, const float* __restrict__ be1,
                 const float* __restrict__ rm1, const float* __restrict__ rv1,
                 const float* __restrict__ g2, const float* __restrict__ be2,
                 const float* __restrict__ rm2, const float* __restrict__ rv2,
                 float* __restrict__ wt1, float* __restrict__ wt2,
                 float* __restrict__ wto1, float* __restrict__ wto2,
                 float* __restrict__ bn)
{
  int i = blockIdx.x * 256 + threadIdx.x;
  if (i < N_WT1) {
    int o = i & 63, c = (i >> 6) & 63, k = i >> 12;
    wt1[i] = w1[(o * 64 + c) * 9 + k];
  } else if (i < N_WT1 + N_WT2) {
    int j = i - N_WT1;
    int o = j & 31, c = (j >> 5) & 63, k = j >> 11;
    wt2[j] = w2[(o * 64 + c) * 9 + k];
  } else if (i < N_WT1 + N_WT2 + N_WTO) {
    int j = i - (N_WT1 + N_WT2);
    int o = j % 27, r = j / 27;
    int k = r % 9, c = r / 9;
    wto1[j] = wo1[(o * 64 + c) * 9 + k];
  } else if (i < N_WT1 + N_WT2 + 2 * N_WTO) {
    int j = i - (N_WT1 + N_WT2 + N_WTO);
    int o = j % 27, r = j / 27;
    int k = r % 9, c = r / 9;
    wto2[j] = wo2[(o * 64 + c) * 9 + k];
  } else if (i < N_WT1 + N_WT2 + 2 * N_WTO + N_BN) {
    int j = i - (N_WT1 + N_WT2 + 2 * N_WTO);
    if (j < 64)       { float inv = g1[j] * rsqrtf(rv1[j] + 1e-5f); bn[j] = inv; }
    else if (j < 128) { int c = j - 64;  float inv = g1[c] * rsqrtf(rv1[c] + 1e-5f); bn[j] = be1[c] - rm1[c] * inv; }
    else if (j < 160) { int c = j - 128; float inv = g2[c] * rsqrtf(rv2[c] + 1e-5f); bn[j] = inv; }
    else              { int c = j - 160; float inv = g2[c] * rsqrtf(rv2[c] + 1e-5f); bn[j] = be2[c] - rm2[c] * inv; }
  }
}

// 3x3 conv 64->27, pad 1. Block = 512 thr = 8 waves, 64 pixels (lane = pixel).
// Wave w handles channels c = w*8..w*8+7; partial acc[27]; LDS cross-wave reduce.
template<bool VIRT>
__global__ __launch_bounds__(512)
void conv27_kernel(const float* __restrict__ xin,
                   const float* __restrict__ pA, const float* __restrict__ pB,
                   const float* __restrict__ wt,    // [(c*9+k)*27+o]
                   const float* __restrict__ bias,  // 27
                   float* __restrict__ off)         // (B,27,H,W)
{
  __shared__ float red[8][64][9];  // stride 9 dwords: gcd(9,32)=1 -> 2-way only
  int t = threadIdx.x;
  int wv = t >> 6, lane = t & 63;
  int wvu = __builtin_amdgcn_readfirstlane(wv);   // wave-uniform for scalar weight loads
  int p = blockIdx.x * 64 + lane;
  int b = __builtin_amdgcn_readfirstlane(p >> 14);
  int hw = p & (HW - 1);
  int h = hw >> 7, w = hw & (Ww - 1);
  float acc[32];
  #pragma unroll
  for (int o = 0; o < 32; o++) acc[o] = 0.f;
  const float* baseA = pA + b * 32 * HW;
  const float* baseB = pB + b * 32 * HW;
  const float* baseX = xin + b * 64 * HW;
  #pragma unroll
  for (int j = 0; j < 8; j++) {
    int c = wvu * 8 + j;  // wave-uniform
    const float* plane = VIRT ? (c < 32 ? baseB + c * HW : baseA + (c - 32) * HW)
                              : baseX + c * HW;
    float xv[9];
    #pragma unroll
    for (int ty = 0; ty < 3; ty++) {
      int yy = h + ty - 1;
      #pragma unroll
      for (int tx = 0; tx < 3; tx++) {
        int xx = w + tx - 1;
        bool ok = ((unsigned)yy < (unsigned)Hh) && ((unsigned)xx < (unsigned)Ww);
        xv[ty * 3 + tx] = ok ? plane[yy * Ww + xx] : 0.f;
      }
    }
    const float* wr = wt + c * 9 * 27;
    #pragma unroll
    for (int k = 0; k < 9; k++) {
      float xk = xv[k];
      #pragma unroll
      for (int o = 0; o < 27; o++) acc[o] = fmaf(wr[k * 27 + o], xk, acc[o]);
    }
  }
  float* op = off + b * 27 * HW + hw;
  #pragma unroll
  for (int ch = 0; ch < 4; ch++) {
    __syncthreads();
    #pragma unroll
    for (int j = 0; j < 8; j++) red[wv][lane][j] = acc[ch * 8 + j];
    __syncthreads();
    int o = ch * 8 + wv;     // this thread reduces (pixel=lane, channel=o)
    if (o < 27) {
      float sum = bias[o];
      #pragma unroll
      for (int u = 0; u < 8; u++) sum += red[u][lane][wv];
      op[o * HW] = sum;      // lanes consecutive -> coalesced
    }
  }
}

// Modulated deformable conv + BN + ReLU (+ optional attention epilogue).
// Block = 512 thr = 8 waves, 64 pixels (lane = pixel). Wave w handles
// channels c = w, w+8, ..., w+56 for all 9 taps; partial acc[O]; LDS reduce.
template<bool VIRT, int O, bool FINAL>
__global__ __launch_bounds__(512)
void deform_kernel(const float* __restrict__ xin,
                   const float* __restrict__ pA, const float* __restrict__ pB,
                   const float* __restrict__ off,   // (B,27,H,W)
                   const float* __restrict__ wt,    // [(k*64+c)*O+o]
                   const float* __restrict__ scale, const float* __restrict__ shift,
                   const float* __restrict__ Aatt, const float* __restrict__ Batt,
                   float* __restrict__ out)         // (B,O,H,W)
{
  __shared__ float red[8][64][9];
  int t = threadIdx.x;
  int wv = t >> 6, lane = t & 63;
  int wvu = __builtin_amdgcn_readfirstlane(wv);
  int p = blockIdx.x * 64 + lane;
  int b = __builtin_amdgcn_readfirstlane(p >> 14);
  int hw = p & (HW - 1);
  int h = hw >> 7, w = hw & (Ww - 1);
  const float* offb = off + b * 27 * HW + hw;
  const float* baseA = pA + b * 32 * HW;
  const float* baseB = pB + b * 32 * HW;
  const float* baseX = xin + b * 64 * HW;
  float acc[O];
  #pragma unroll
  for (int o = 0; o < O; o++) acc[o] = 0.f;

  for (int k = 0; k < 9; k++) {
    float dy = offb[(2 * k) * HW];
    float dx = offb[(2 * k + 1) * HW];
    float mm = offb[(18 + k) * HW];
    float m = 1.f / (1.f + __expf(-mm));
    float ys = (float)(h + k / 3 - 1) + dy;
    float xs = (float)(w + k % 3 - 1) + dx;
    float y0f = floorf(ys), x0f = floorf(xs);
    float fy = ys - y0f, fx = xs - x0f;
    int y0 = (int)y0f, x0 = (int)x0f;
    int y1 = y0 + 1, x1 = x0 + 1;
    float vy0 = ((unsigned)y0 < (unsigned)Hh) ? 1.f : 0.f;
    float vy1 = ((unsigned)y1 < (unsigned)Hh) ? 1.f : 0.f;
    float vx0 = ((unsigned)x0 < (unsigned)Ww) ? 1.f : 0.f;
    float vx1 = ((unsigned)x1 < (unsigned)Ww) ? 1.f : 0.f;
    int cy0 = min(max(y0, 0), Hh - 1), cy1 = min(max(y1, 0), Hh - 1);
    int cx0 = min(max(x0, 0), Ww - 1), cx1 = min(max(x1, 0), Ww - 1);
    int i00 = cy0 * Ww + cx0, i01 = cy0 * Ww + cx1;
    int i10 = cy1 * Ww + cx0, i11 = cy1 * Ww + cx1;
    float w00 = (1.f - fy) * (1.f - fx) * m * vy0 * vx0;
    float w01 = (1.f - fy) * fx * m * vy0 * vx1;
    float w10 = fy * (1.f - fx) * m * vy1 * vx0;
    float w11 = fy * fx * m * vy1 * vx1;
    const float* wk = wt + k * 64 * O;
    #pragma unroll
    for (int j = 0; j < 8; j++) {
      int c = wvu + 8 * j;  // wave-uniform
      const float* plane = VIRT ? (c < 32 ? baseB + c * HW : baseA + (c - 32) * HW)
                                : baseX + c * HW;
      float s = w00 * plane[i00] + w01 * plane[i01] + w10 * plane[i10] + w11 * plane[i11];
      const float* wr = wk + c * O;
      #pragma unroll
      for (int o = 0; o < O; o++) acc[o] = fmaf(wr[o], s, acc[o]);
    }
  }

  float fmul = 1.f;
  if (FINAL) {
    fmul = (1.f - Aatt[b * HW + hw]) * Batt[b * HW + hw];
  }
  float* op = out + b * O * HW + hw;
  for (int ch = 0; ch < O / 8; ch++) {
    __syncthreads();
    #pragma unroll
    for (int j = 0; j < 8; j++) red[wv][lane][j] = acc[ch * 8 + j];
    __syncthreads();
    int o = ch * 8 + wv;     // this thread reduces (pixel=lane, channel=o)
    float sum = 0.f;
    #pragma unroll
    for (int u = 0; u < 8; u++) sum += red[u][lane][wv];
    float v = fmaf(sum, scale[o], shift[o]);
    v = fmaxf(v, 0.f);
    if (FINAL) v *= fmul;
    op[o * HW] = v;          // lanes consecutive -> coalesced
  }
}

} // namespace

extern "C" void kernel_launch(void* const* d_in, const int* in_sizes, int n_in,
                              void* d_out, int out_size, void* d_ws, size_t ws_size,
                              hipStream_t stream) {
  const float* pA   = (const float*)d_in[1];
  const float* pB   = (const float*)d_in[2];
  const float* Aatt = (const float*)d_in[3];
  const float* Batt = (const float*)d_in[4];
  const float* wo1  = (const float*)d_in[5];
  const float* bo1  = (const float*)d_in[6];
  const float* w1   = (const float*)d_in[7];
  const float* g1   = (const float*)d_in[8];
  const float* be1  = (const float*)d_in[9];
  const float* rm1  = (const float*)d_in[10];
  const float* rv1  = (const float*)d_in[11];
  const float* wo2  = (const float*)d_in[12];
  const float* bo2  = (const float*)d_in[13];
  const float* w2   = (const float*)d_in[14];
  const float* g2   = (const float*)d_in[15];
  const float* be2  = (const float*)d_in[16];
  const float* rm2  = (const float*)d_in[17];
  const float* rv2  = (const float*)d_in[18];

  float* ws   = (float*)d_ws;
  float* off  = ws;                       // 4*27*16384 floats
  float* out1 = off + Bn * 27 * HW;       // 4*64*16384 floats
  float* wt1  = out1 + Bn * 64 * HW;
  float* wt2  = wt1 + N_WT1;
  float* wto1 = wt2 + N_WT2;
  float* wto2 = wto1 + N_WTO;
  float* bn   = wto2 + N_WTO;             // 192 floats
  float* sc1 = bn, * sh1 = bn + 64, * sc2 = bn + 128, * sh2 = bn + 160;

  int prep_n = N_WT1 + N_WT2 + 2 * N_WTO + N_BN;
  prep_kernel<<<(prep_n + 255) / 256, 256, 0, stream>>>(
      w1, w2, wo1, wo2, g1, be1, rm1, rv1, g2, be2, rm2, rv2,
      wt1, wt2, wto1, wto2, bn);

  // 65536 pixels / 64 per block = 1024 blocks, 512 threads each
  conv27_kernel<true><<<1024, 512, 0, stream>>>(pA, pA, pB, wto1, bo1, off);
  deform_kernel<true, 64, false><<<1024, 512, 0, stream>>>(
      pA, pA, pB, off, wt1, sc1, sh1, nullptr, nullptr, out1);

  conv27_kernel<false><<<1024, 512, 0, stream>>>(out1, pA, pB, wto2, bo2, off);
  deform_kernel<false, 32, true><<<1024, 512, 0, stream>>>(
      out1, pA, pB, off, wt2, sc2, sh2, Aatt, Batt, (float*)d_out);
}

// Round 5
// 412.488 us; speedup vs baseline: 1.9584x; 1.9544x over previous
//
#include <hip/hip_runtime.h>

namespace {
constexpr int Hh = 128, Ww = 128, HW = Hh * Ww;
constexpr int Bn = 4;

using h4 = __attribute__((ext_vector_type(4))) _Float16;
using h8 = __attribute__((ext_vector_type(8))) _Float16;
using f4 = __attribute__((ext_vector_type(4))) float;

// ---- workspace layout (f32 slots) ----
constexpr size_t OFF_OFF  = 0;                       // 4*27*HW f32
constexpr size_t XH1_OFF  = OFF_OFF + (size_t)Bn*27*HW;        // 4*HW*64 f16 -> /2 slots
constexpr size_t OUT1_OFF = XH1_OFF + (size_t)Bn*HW*32;        // (64 f16 per px = 32 f32 slots)
constexpr size_t WA1_OFF  = OUT1_OFF + (size_t)Bn*HW*32;       // 9*64*64 f16 = 18432 slots
constexpr size_t WA2_OFF  = WA1_OFF + 18432;                   // 9*32*64 f16 = 9216 slots
constexpr size_t WO1_OFF  = WA2_OFF + 9216;
constexpr size_t WO2_OFF  = WO1_OFF + 9216;
constexpr size_t BN_OFF   = WO2_OFF + 9216;                    // 256 f32

constexpr int E1 = 9 * 64 * 64;   // wA1
constexpr int E2 = 9 * 32 * 64;   // wA2
constexpr int E3 = 9 * 32 * 64;   // wO1 (27 real rows, 5 zero pad)
constexpr int E4 = 9 * 32 * 64;   // wO2
constexpr int E5 = 256;           // bn: sc1[64] sh1[64] sc2[32] sh2[32] bo1[32] bo2[32]
constexpr int PREP_N = E1 + E2 + E3 + E4 + E5;

__global__ __launch_bounds__(256)
void prep_kernel(const float* __restrict__ w1, const float* __restrict__ w2,
                 const float* __restrict__ wo1, const float* __restrict__ wo2,
                 const float* __restrict__ g1, const float* __restrict__ be1,
                 const float* __restrict__ rm1, const float* __restrict__ rv1,
                 const float* __restrict__ g2, const float* __restrict__ be2,
                 const float* __restrict__ rm2, const float* __restrict__ rv2,
                 const float* __restrict__ bo1, const float* __restrict__ bo2,
                 _Float16* __restrict__ wA1, _Float16* __restrict__ wA2,
                 _Float16* __restrict__ wO1, _Float16* __restrict__ wO2,
                 float* __restrict__ bn)
{
  int i = blockIdx.x * 256 + threadIdx.x;
  if (i < E1) {
    int c = i & 63, o = (i >> 6) & 63, k = i >> 12;
    wA1[i] = (_Float16)w1[(o * 64 + c) * 9 + k];
  } else if (i < E1 + E2) {
    int j = i - E1;
    int c = j & 63, o = (j >> 6) & 31, k = j >> 11;
    wA2[j] = (_Float16)w2[(o * 64 + c) * 9 + k];
  } else if (i < E1 + E2 + E3) {
    int j = i - (E1 + E2);
    int c = j & 63, o = (j >> 6) & 31, k = j >> 11;
    wO1[j] = (o < 27) ? (_Float16)wo1[(o * 64 + c) * 9 + k] : (_Float16)0.f;
  } else if (i < E1 + E2 + E3 + E4) {
    int j = i - (E1 + E2 + E3);
    int c = j & 63, o = (j >> 6) & 31, k = j >> 11;
    wO2[j] = (o < 27) ? (_Float16)wo2[(o * 64 + c) * 9 + k] : (_Float16)0.f;
  } else if (i < PREP_N) {
    int j = i - (E1 + E2 + E3 + E4);
    if (j < 64)       { bn[j] = g1[j] * rsqrtf(rv1[j] + 1e-5f); }
    else if (j < 128) { int c = j - 64;  float inv = g1[c] * rsqrtf(rv1[c] + 1e-5f); bn[j] = be1[c] - rm1[c] * inv; }
    else if (j < 160) { int c = j - 128; bn[j] = g2[c] * rsqrtf(rv2[c] + 1e-5f); }
    else if (j < 192) { int c = j - 160; float inv = g2[c] * rsqrtf(rv2[c] + 1e-5f); bn[j] = be2[c] - rm2[c] * inv; }
    else if (j < 224) { int c = j - 192; bn[j] = (c < 27) ? bo1[c] : 0.f; }
    else              { int c = j - 224; bn[j] = (c < 27) ? bo2[c] : 0.f; }
  }
}

// NCHW concat(pB,pA) -> NHWC fp16. Block = 64 px * 64 ch, LDS transpose.
__global__ __launch_bounds__(256)
void xcat_kernel(const float* __restrict__ pA, const float* __restrict__ pB,
                 _Float16* __restrict__ xh)
{
  __shared__ float tile[64][65];
  int t = threadIdx.x;
  int pxbase = blockIdx.x * 64;
  int b = pxbase >> 14, hwbase = pxbase & (HW - 1);
  int lane = t & 63, cq = t >> 6;
  #pragma unroll
  for (int i = 0; i < 16; i++) {
    int cc = i * 4 + cq;
    const float* src = (cc < 32) ? (pB + ((size_t)b * 32 + cc) * HW)
                                 : (pA + ((size_t)b * 32 + cc - 32) * HW);
    tile[lane][cc] = src[hwbase + lane];
  }
  __syncthreads();
  int px = t >> 2, cg = t & 3;
  h8 ra, rb;
  #pragma unroll
  for (int j = 0; j < 8; j++) {
    ra[j] = (_Float16)tile[px][cg * 16 + j];
    rb[j] = (_Float16)tile[px][cg * 16 + 8 + j];
  }
  _Float16* dst = xh + (size_t)(pxbase + px) * 64 + cg * 16;
  *(h8*)dst = ra;
  *(h8*)(dst + 8) = rb;
}

// 3x3 conv 64->27(pad32) via direct-global MFMA implicit GEMM.
// Block 256 = 4 waves; 64 px (one h-row segment); wave handles 16 px.
__global__ __launch_bounds__(256)
void convoff_kernel(const _Float16* __restrict__ xh, const _Float16* __restrict__ wO,
                    const float* __restrict__ bo, float* __restrict__ offo)
{
  int t = threadIdx.x, wv = t >> 6, l = t & 63;
  int l15 = l & 15, lg = l >> 4;
  int pxbase = blockIdx.x * 64;
  int b = pxbase >> 14, hwbase = pxbase & (HW - 1);
  int h = hwbase >> 7, wb = hwbase & 127;
  int pxl = wv * 16 + l15;
  int wpix = wb + pxl;
  f4 acc0 = {0.f, 0.f, 0.f, 0.f};
  f4 acc1 = {0.f, 0.f, 0.f, 0.f};
  const _Float16* xrowbase = xh + (size_t)b * HW * 64;
  for (int k = 0; k < 9; k++) {
    int dy = k / 3 - 1, dx = k % 3 - 1;
    int yy = h + dy;
    if ((unsigned)yy >= 128u) continue;          // uniform per block
    int xx = wpix + dx;
    bool valid = (unsigned)xx < 128u;
    const _Float16* brow = xrowbase + ((size_t)yy * 128 + xx) * 64;
    #pragma unroll
    for (int kk = 0; kk < 2; kk++) {
      h8 bf = {(_Float16)0.f, (_Float16)0.f, (_Float16)0.f, (_Float16)0.f,
               (_Float16)0.f, (_Float16)0.f, (_Float16)0.f, (_Float16)0.f};
      if (valid) bf = *(const h8*)(brow + kk * 32 + lg * 8);
      const _Float16* arow = wO + ((size_t)k * 32 + l15) * 64 + kk * 32 + lg * 8;
      h8 af0 = *(const h8*)(arow);
      h8 af1 = *(const h8*)(arow + 16 * 64);
      acc0 = __builtin_amdgcn_mfma_f32_16x16x32_f16(af0, bf, acc0, 0, 0, 0);
      acc1 = __builtin_amdgcn_mfma_f32_16x16x32_f16(af1, bf, acc1, 0, 0, 0);
    }
  }
  int hwpx = hwbase + pxl;
  float* ob = offo + (size_t)b * 27 * HW + hwpx;
  int o0 = lg * 4;
  f4 b0 = *(const f4*)(bo + o0);
  #pragma unroll
  for (int r = 0; r < 4; r++) ob[(o0 + r) * HW] = acc0[r] + b0[r];
  int o1 = 16 + lg * 4;
  f4 b1 = *(const f4*)(bo + o1);
  #pragma unroll
  for (int r = 0; r < 4; r++) if (o1 + r < 27) ob[(o1 + r) * HW] = acc1[r] + b1[r];
}

// Modulated deformable conv via gather->LDS(fp16, XOR-swizzled) + MFMA.
// Block 256 = 4 waves, 64 px. M = 64 (stage1, NHWC f16 out) or 32 (stage2, NCHW f32 out).
template<int M, bool FINAL>
__global__ __launch_bounds__(256)
void deform_kernel(const _Float16* __restrict__ xh, const float* __restrict__ offo,
                   const _Float16* __restrict__ wA,
                   const float* __restrict__ scale, const float* __restrict__ shift,
                   const float* __restrict__ Aatt, const float* __restrict__ Batt,
                   _Float16* __restrict__ outh, float* __restrict__ outf)
{
  __shared__ char smem[64 * 128];   // sampled [64 px][64 ch] f16, granule-swizzled
  int t = threadIdx.x, wv = t >> 6, l = t & 63;
  int l15 = l & 15, lg = l >> 4;
  int pxbase = blockIdx.x * 64;
  int b = pxbase >> 14, hwbase = pxbase & (HW - 1);
  int h = hwbase >> 7, wb = hwbase & 127;
  const float* offb = offo + (size_t)b * 27 * HW;
  const _Float16* xb = xh + (size_t)b * HW * 64;
  constexpr int MT = M / 16;
  f4 acc[MT];
  #pragma unroll
  for (int mt = 0; mt < MT; mt++) acc[mt] = f4{0.f, 0.f, 0.f, 0.f};
  int c = l;                         // gather: lane = channel

  for (int k = 0; k < 9; k++) {
    int kdy = k / 3 - 1, kdx = k % 3 - 1;
    // ---- gather phase: this wave fills px rows wv*16 .. wv*16+15 ----
    for (int i = 0; i < 16; i++) {
      int pxl = wv * 16 + i;
      int hwpx = hwbase + pxl;
      float dy = offb[(2 * k) * HW + hwpx];
      float dx = offb[(2 * k + 1) * HW + hwpx];
      float mm = offb[(18 + k) * HW + hwpx];
      float m = 1.f / (1.f + __expf(-mm));
      float ys = (float)(h + kdy) + dy;
      float xs = (float)(wb + pxl + kdx) + dx;
      float y0f = floorf(ys), x0f = floorf(xs);
      float fy = ys - y0f, fx = xs - x0f;
      int y0 = (int)y0f, x0 = (int)x0f;
      int y1 = y0 + 1, x1 = x0 + 1;
      float vy0 = ((unsigned)y0 < 128u) ? 1.f : 0.f;
      float vy1 = ((unsigned)y1 < 128u) ? 1.f : 0.f;
      float vx0 = ((unsigned)x0 < 128u) ? 1.f : 0.f;
      float vx1 = ((unsigned)x1 < 128u) ? 1.f : 0.f;
      int cy0 = min(max(y0, 0), 127), cy1 = min(max(y1, 0), 127);
      int cx0 = min(max(x0, 0), 127), cx1 = min(max(x1, 0), 127);
      int r00 = (cy0 * 128 + cx0) * 64, r01 = (cy0 * 128 + cx1) * 64;
      int r10 = (cy1 * 128 + cx0) * 64, r11 = (cy1 * 128 + cx1) * 64;
      float w00 = (1.f - fy) * (1.f - fx) * vy0 * vx0;
      float w01 = (1.f - fy) * fx * vy0 * vx1;
      float w10 = fy * (1.f - fx) * vy1 * vx0;
      float w11 = fy * fx * vy1 * vx1;
      float s = w00 * (float)xb[r00 + c] + w01 * (float)xb[r01 + c]
              + w10 * (float)xb[r10 + c] + w11 * (float)xb[r11 + c];
      s *= m;
      unsigned wa = (unsigned)(pxl * 128 + ((c * 2) ^ ((pxl & 7) << 4)));
      *(_Float16*)(smem + wa) = (_Float16)s;
    }
    __syncthreads();
    // ---- MFMA phase: wave's px tile = wv*16 + (l&15) ----
    int pxr = wv * 16 + l15;
    #pragma unroll
    for (int kk = 0; kk < 2; kk++) {
      unsigned ra = (unsigned)(pxr * 128 + ((kk * 64 + lg * 16) ^ ((pxr & 7) << 4)));
      h8 bf = *(const h8*)(smem + ra);
      #pragma unroll
      for (int mt = 0; mt < MT; mt++) {
        h8 af = *(const h8*)(wA + ((size_t)k * M + mt * 16 + l15) * 64 + kk * 32 + lg * 8);
        acc[mt] = __builtin_amdgcn_mfma_f32_16x16x32_f16(af, bf, acc[mt], 0, 0, 0);
      }
    }
    __syncthreads();
  }

  // ---- epilogue: BN + ReLU (+ attention), C-layout col=l&15(px), row=lg*4+r ----
  int pxl = wv * 16 + l15;
  int hwpx = hwbase + pxl;
  int pxg = pxbase + pxl;
  if (!FINAL) {
    #pragma unroll
    for (int mt = 0; mt < MT; mt++) {
      int o0 = mt * 16 + lg * 4;
      f4 sc = *(const f4*)(scale + o0);
      f4 sh = *(const f4*)(shift + o0);
      h4 o4;
      #pragma unroll
      for (int r = 0; r < 4; r++) {
        o4[r] = (_Float16)fmaxf(fmaf(acc[mt][r], sc[r], sh[r]), 0.f);
      }
      *(h4*)(outh + (size_t)pxg * 64 + o0) = o4;
    }
  } else {
    float fm = (1.f - Aatt[(size_t)b * HW + hwpx]) * Batt[(size_t)b * HW + hwpx];
    #pragma unroll
    for (int mt = 0; mt < MT; mt++) {
      int o0 = mt * 16 + lg * 4;
      f4 sc = *(const f4*)(scale + o0);
      f4 sh = *(const f4*)(shift + o0);
      #pragma unroll
      for (int r = 0; r < 4; r++) {
        float v = fmaxf(fmaf(acc[mt][r], sc[r], sh[r]), 0.f) * fm;
        outf[((size_t)b * 32 + o0 + r) * HW + hwpx] = v;
      }
    }
  }
}

} // namespace

extern "C" void kernel_launch(void* const* d_in, const int* in_sizes, int n_in,
                              void* d_out, int out_size, void* d_ws, size_t ws_size,
                              hipStream_t stream) {
  const float* pA   = (const float*)d_in[1];
  const float* pB   = (const float*)d_in[2];
  const float* Aatt = (const float*)d_in[3];
  const float* Batt = (const float*)d_in[4];
  const float* wo1  = (const float*)d_in[5];
  const float* bo1  = (const float*)d_in[6];
  const float* w1   = (const float*)d_in[7];
  const float* g1   = (const float*)d_in[8];
  const float* be1  = (const float*)d_in[9];
  const float* rm1  = (const float*)d_in[10];
  const float* rv1  = (const float*)d_in[11];
  const float* wo2  = (const float*)d_in[12];
  const float* bo2  = (const float*)d_in[13];
  const float* w2   = (const float*)d_in[14];
  const float* g2   = (const float*)d_in[15];
  const float* be2  = (const float*)d_in[16];
  const float* rm2  = (const float*)d_in[17];
  const float* rv2  = (const float*)d_in[18];

  float* ws = (float*)d_ws;
  float*     off   = ws + OFF_OFF;
  _Float16*  xh1   = (_Float16*)(ws + XH1_OFF);
  _Float16*  out1h = (_Float16*)(ws + OUT1_OFF);
  _Float16*  wA1   = (_Float16*)(ws + WA1_OFF);
  _Float16*  wA2   = (_Float16*)(ws + WA2_OFF);
  _Float16*  wO1   = (_Float16*)(ws + WO1_OFF);
  _Float16*  wO2   = (_Float16*)(ws + WO2_OFF);
  float*     bn    = ws + BN_OFF;
  float* sc1 = bn;       float* sh1 = bn + 64;
  float* sc2 = bn + 128; float* sh2 = bn + 160;
  float* bO1 = bn + 192; float* bO2 = bn + 224;

  prep_kernel<<<(PREP_N + 255) / 256, 256, 0, stream>>>(
      w1, w2, wo1, wo2, g1, be1, rm1, rv1, g2, be2, rm2, rv2,
      bo1, bo2, wA1, wA2, wO1, wO2, bn);

  xcat_kernel<<<1024, 256, 0, stream>>>(pA, pB, xh1);

  // stage 1
  convoff_kernel<<<1024, 256, 0, stream>>>(xh1, wO1, bO1, off);
  deform_kernel<64, false><<<1024, 256, 0, stream>>>(
      xh1, off, wA1, sc1, sh1, nullptr, nullptr, out1h, nullptr);

  // stage 2
  convoff_kernel<<<1024, 256, 0, stream>>>(out1h, wO2, bO2, off);
  deform_kernel<32, true><<<1024, 256, 0, stream>>>(
      out1h, off, wA2, sc2, sh2, Aatt, Batt, nullptr, (float*)d_out);
}

// Round 6
// 268.843 us; speedup vs baseline: 3.0048x; 1.5343x over previous
//
#include <hip/hip_runtime.h>

namespace {
constexpr int Hh = 128, Ww = 128, HW = Hh * Ww;
constexpr int Bn = 4;

using h4 = __attribute__((ext_vector_type(4))) _Float16;
using h8 = __attribute__((ext_vector_type(8))) _Float16;
using f4 = __attribute__((ext_vector_type(4))) float;
using g2 = __attribute__((ext_vector_type(2))) __fp16;

// ---- workspace layout (f32 slots) ----
constexpr size_t OFF_OFF  = 0;                       // 4*27*HW f32
constexpr size_t XH1_OFF  = OFF_OFF + (size_t)Bn*27*HW;        // 4*HW*64 f16
constexpr size_t OUT1_OFF = XH1_OFF + (size_t)Bn*HW*32;
constexpr size_t WA1_OFF  = OUT1_OFF + (size_t)Bn*HW*32;       // 9*64*64 f16
constexpr size_t WA2_OFF  = WA1_OFF + 18432;                   // 9*32*64 f16
constexpr size_t WO1_OFF  = WA2_OFF + 9216;
constexpr size_t WO2_OFF  = WO1_OFF + 9216;
constexpr size_t BN_OFF   = WO2_OFF + 9216;                    // 256 f32

constexpr int E1 = 9 * 64 * 64;   // wA1
constexpr int E2 = 9 * 32 * 64;   // wA2
constexpr int E3 = 9 * 32 * 64;   // wO1 (27 real rows, 5 zero pad)
constexpr int E4 = 9 * 32 * 64;   // wO2
constexpr int E5 = 256;           // bn: sc1[64] sh1[64] sc2[32] sh2[32] bo1[32] bo2[32]
constexpr int PREP_N = E1 + E2 + E3 + E4 + E5;

__global__ __launch_bounds__(256)
void prep_kernel(const float* __restrict__ w1, const float* __restrict__ w2,
                 const float* __restrict__ wo1, const float* __restrict__ wo2,
                 const float* __restrict__ g1, const float* __restrict__ be1,
                 const float* __restrict__ rm1, const float* __restrict__ rv1,
                 const float* __restrict__ g2v, const float* __restrict__ be2,
                 const float* __restrict__ rm2, const float* __restrict__ rv2,
                 const float* __restrict__ bo1, const float* __restrict__ bo2,
                 _Float16* __restrict__ wA1, _Float16* __restrict__ wA2,
                 _Float16* __restrict__ wO1, _Float16* __restrict__ wO2,
                 float* __restrict__ bn)
{
  int i = blockIdx.x * 256 + threadIdx.x;
  if (i < E1) {
    int c = i & 63, o = (i >> 6) & 63, k = i >> 12;
    wA1[i] = (_Float16)w1[(o * 64 + c) * 9 + k];
  } else if (i < E1 + E2) {
    int j = i - E1;
    int c = j & 63, o = (j >> 6) & 31, k = j >> 11;
    wA2[j] = (_Float16)w2[(o * 64 + c) * 9 + k];
  } else if (i < E1 + E2 + E3) {
    int j = i - (E1 + E2);
    int c = j & 63, o = (j >> 6) & 31, k = j >> 11;
    wO1[j] = (o < 27) ? (_Float16)wo1[(o * 64 + c) * 9 + k] : (_Float16)0.f;
  } else if (i < E1 + E2 + E3 + E4) {
    int j = i - (E1 + E2 + E3);
    int c = j & 63, o = (j >> 6) & 31, k = j >> 11;
    wO2[j] = (o < 27) ? (_Float16)wo2[(o * 64 + c) * 9 + k] : (_Float16)0.f;
  } else if (i < PREP_N) {
    int j = i - (E1 + E2 + E3 + E4);
    if (j < 64)       { bn[j] = g1[j] * rsqrtf(rv1[j] + 1e-5f); }
    else if (j < 128) { int c = j - 64;  float inv = g1[c] * rsqrtf(rv1[c] + 1e-5f); bn[j] = be1[c] - rm1[c] * inv; }
    else if (j < 160) { int c = j - 128; bn[j] = g2v[c] * rsqrtf(rv2[c] + 1e-5f); }
    else if (j < 192) { int c = j - 160; float inv = g2v[c] * rsqrtf(rv2[c] + 1e-5f); bn[j] = be2[c] - rm2[c] * inv; }
    else if (j < 224) { int c = j - 192; bn[j] = (c < 27) ? bo1[c] : 0.f; }
    else              { int c = j - 224; bn[j] = (c < 27) ? bo2[c] : 0.f; }
  }
}

// NCHW concat(pB,pA) -> NHWC fp16. Block = 64 px * 64 ch, LDS transpose.
__global__ __launch_bounds__(256)
void xcat_kernel(const float* __restrict__ pA, const float* __restrict__ pB,
                 _Float16* __restrict__ xh)
{
  __shared__ float tile[64][65];
  int t = threadIdx.x;
  int pxbase = blockIdx.x * 64;
  int b = pxbase >> 14, hwbase = pxbase & (HW - 1);
  int lane = t & 63, cq = t >> 6;
  #pragma unroll
  for (int i = 0; i < 16; i++) {
    int cc = i * 4 + cq;
    const float* src = (cc < 32) ? (pB + ((size_t)b * 32 + cc) * HW)
                                 : (pA + ((size_t)b * 32 + cc - 32) * HW);
    tile[lane][cc] = src[hwbase + lane];
  }
  __syncthreads();
  int px = t >> 2, cg = t & 3;
  h8 ra, rb;
  #pragma unroll
  for (int j = 0; j < 8; j++) {
    ra[j] = (_Float16)tile[px][cg * 16 + j];
    rb[j] = (_Float16)tile[px][cg * 16 + 8 + j];
  }
  _Float16* dst = xh + (size_t)(pxbase + px) * 64 + cg * 16;
  *(h8*)dst = ra;
  *(h8*)(dst + 8) = rb;
}

// 3x3 conv 64->27(pad32) via direct-global MFMA implicit GEMM.
__global__ __launch_bounds__(256)
void convoff_kernel(const _Float16* __restrict__ xh, const _Float16* __restrict__ wO,
                    const float* __restrict__ bo, float* __restrict__ offo)
{
  int t = threadIdx.x, wv = t >> 6, l = t & 63;
  int l15 = l & 15, lg = l >> 4;
  int pxbase = blockIdx.x * 64;
  int b = pxbase >> 14, hwbase = pxbase & (HW - 1);
  int h = hwbase >> 7, wb = hwbase & 127;
  int pxl = wv * 16 + l15;
  int wpix = wb + pxl;
  f4 acc0 = {0.f, 0.f, 0.f, 0.f};
  f4 acc1 = {0.f, 0.f, 0.f, 0.f};
  const _Float16* xrowbase = xh + (size_t)b * HW * 64;
  for (int k = 0; k < 9; k++) {
    int dy = k / 3 - 1, dx = k % 3 - 1;
    int yy = h + dy;
    if ((unsigned)yy >= 128u) continue;          // uniform per block
    int xx = wpix + dx;
    bool valid = (unsigned)xx < 128u;
    const _Float16* brow = xrowbase + ((size_t)yy * 128 + xx) * 64;
    #pragma unroll
    for (int kk = 0; kk < 2; kk++) {
      h8 bf = {(_Float16)0.f, (_Float16)0.f, (_Float16)0.f, (_Float16)0.f,
               (_Float16)0.f, (_Float16)0.f, (_Float16)0.f, (_Float16)0.f};
      if (valid) bf = *(const h8*)(brow + kk * 32 + lg * 8);
      const _Float16* arow = wO + ((size_t)k * 32 + l15) * 64 + kk * 32 + lg * 8;
      h8 af0 = *(const h8*)(arow);
      h8 af1 = *(const h8*)(arow + 16 * 64);
      acc0 = __builtin_amdgcn_mfma_f32_16x16x32_f16(af0, bf, acc0, 0, 0, 0);
      acc1 = __builtin_amdgcn_mfma_f32_16x16x32_f16(af1, bf, acc1, 0, 0, 0);
    }
  }
  int hwpx = hwbase + pxl;
  float* ob = offo + (size_t)b * 27 * HW + hwpx;
  int o0 = lg * 4;
  f4 b0 = *(const f4*)(bo + o0);
  #pragma unroll
  for (int r = 0; r < 4; r++) ob[(o0 + r) * HW] = acc0[r] + b0[r];
  int o1 = 16 + lg * 4;
  f4 b1 = *(const f4*)(bo + o1);
  #pragma unroll
  for (int r = 0; r < 4; r++) if (o1 + r < 27) ob[(o1 + r) * HW] = acc1[r] + b1[r];
}

// Modulated deformable conv: LDS-precomputed bilinear setup + f16x2 gathers + MFMA.
// Block 256 = 4 waves, 64 px.
template<int M, bool FINAL>
__global__ __launch_bounds__(256)
void deform_kernel(const _Float16* __restrict__ xh, const float* __restrict__ offo,
                   const _Float16* __restrict__ wA,
                   const float* __restrict__ scale, const float* __restrict__ shift,
                   const float* __restrict__ Aatt, const float* __restrict__ Batt,
                   _Float16* __restrict__ outh, float* __restrict__ outf)
{
  __shared__ __align__(16) float sW[576 * 4];   // w00..w11 (mask folded)
  __shared__ __align__(16) int   sR[576 * 4];   // corner byte offsets
  __shared__ char smem[64 * 128];               // sampled [64 px][64 ch] f16, swizzled
  int t = threadIdx.x, wv = t >> 6, l = t & 63;
  int l15 = l & 15, lg = l >> 4;
  int pxbase = blockIdx.x * 64;
  int b = pxbase >> 14, hwbase = pxbase & (HW - 1);
  int h = hwbase >> 7, wb = hwbase & 127;
  const float* offb = offo + (size_t)b * 27 * HW;
  const _Float16* xb = xh + (size_t)b * HW * 64;
  const char* xbb = (const char*)xb;
  constexpr int MT = M / 16;
  f4 acc[MT];
  #pragma unroll
  for (int mt = 0; mt < MT; mt++) acc[mt] = f4{0.f, 0.f, 0.f, 0.f};

  // ---- setup phase: all 576 (k,px) bilinear configs, once ----
  for (int it = t; it < 576; it += 256) {
    int k = it >> 6, px = it & 63;
    int hwpx = hwbase + px;
    float dy = offb[(2 * k) * HW + hwpx];
    float dx = offb[(2 * k + 1) * HW + hwpx];
    float mm = offb[(18 + k) * HW + hwpx];
    float m = 1.f / (1.f + __expf(-mm));
    float ys = (float)(h + k / 3 - 1) + dy;
    float xs = (float)(wb + px + k % 3 - 1) + dx;
    float y0f = floorf(ys), x0f = floorf(xs);
    float fy = ys - y0f, fx = xs - x0f;
    int y0 = (int)y0f, x0 = (int)x0f;
    int y1 = y0 + 1, x1 = x0 + 1;
    float vy0 = ((unsigned)y0 < 128u) ? 1.f : 0.f;
    float vy1 = ((unsigned)y1 < 128u) ? 1.f : 0.f;
    float vx0 = ((unsigned)x0 < 128u) ? 1.f : 0.f;
    float vx1 = ((unsigned)x1 < 128u) ? 1.f : 0.f;
    int cy0 = min(max(y0, 0), 127), cy1 = min(max(y1, 0), 127);
    int cx0 = min(max(x0, 0), 127), cx1 = min(max(x1, 0), 127);
    sW[it * 4 + 0] = (1.f - fy) * (1.f - fx) * m * vy0 * vx0;
    sW[it * 4 + 1] = (1.f - fy) * fx * m * vy0 * vx1;
    sW[it * 4 + 2] = fy * (1.f - fx) * m * vy1 * vx0;
    sW[it * 4 + 3] = fy * fx * m * vy1 * vx1;
    sR[it * 4 + 0] = (cy0 * 128 + cx0) * 128;   // byte offsets into NHWC f16
    sR[it * 4 + 1] = (cy0 * 128 + cx1) * 128;
    sR[it * 4 + 2] = (cy1 * 128 + cx0) * 128;
    sR[it * 4 + 3] = (cy1 * 128 + cx1) * 128;
  }
  __syncthreads();

  int half = l >> 5;       // 0/1: which of the 2 pixels this lane serves
  int cp = l & 31;         // channel pair 0..31
  int cb = cp * 4;         // byte offset of f16x2 within the 128B channel row

  for (int k = 0; k < 9; k++) {
    // ---- gather: 8 iters x 2 px, f16x2 per lane, f32 lerp ----
    #pragma unroll
    for (int i = 0; i < 8; i++) {
      int px = wv * 16 + i * 2 + half;
      int item = (k << 6) + px;
      f4 wgt = *(const f4*)&sW[item * 4];
      int r0 = sR[item * 4 + 0], r1 = sR[item * 4 + 1];
      int r2 = sR[item * 4 + 2], r3 = sR[item * 4 + 3];
      g2 v00 = *(const g2*)(xbb + r0 + cb);
      g2 v01 = *(const g2*)(xbb + r1 + cb);
      g2 v10 = *(const g2*)(xbb + r2 + cb);
      g2 v11 = *(const g2*)(xbb + r3 + cb);
      float lo = wgt[0] * (float)v00[0] + wgt[1] * (float)v01[0]
               + wgt[2] * (float)v10[0] + wgt[3] * (float)v11[0];
      float hi = wgt[0] * (float)v00[1] + wgt[1] * (float)v01[1]
               + wgt[2] * (float)v10[1] + wgt[3] * (float)v11[1];
      g2 pk = __builtin_amdgcn_cvt_pkrtz(lo, hi);
      unsigned wa = (unsigned)(px * 128 + (cb ^ ((px & 7) << 4)));
      *(g2*)(smem + wa) = pk;
    }
    __syncthreads();
    // ---- MFMA phase: wave's px tile = wv*16 + (l&15) ----
    int pxr = wv * 16 + l15;
    #pragma unroll
    for (int kk = 0; kk < 2; kk++) {
      unsigned ra = (unsigned)(pxr * 128 + ((kk * 64 + lg * 16) ^ ((pxr & 7) << 4)));
      h8 bf = *(const h8*)(smem + ra);
      #pragma unroll
      for (int mt = 0; mt < MT; mt++) {
        h8 af = *(const h8*)(wA + ((size_t)k * M + mt * 16 + l15) * 64 + kk * 32 + lg * 8);
        acc[mt] = __builtin_amdgcn_mfma_f32_16x16x32_f16(af, bf, acc[mt], 0, 0, 0);
      }
    }
    __syncthreads();
  }

  // ---- epilogue: BN + ReLU (+ attention), C-layout col=l&15(px), row=lg*4+r ----
  int pxl = wv * 16 + l15;
  int hwpx = hwbase + pxl;
  int pxg = pxbase + pxl;
  if (!FINAL) {
    #pragma unroll
    for (int mt = 0; mt < MT; mt++) {
      int o0 = mt * 16 + lg * 4;
      f4 sc = *(const f4*)(scale + o0);
      f4 sh = *(const f4*)(shift + o0);
      h4 o4;
      #pragma unroll
      for (int r = 0; r < 4; r++) {
        o4[r] = (_Float16)fmaxf(fmaf(acc[mt][r], sc[r], sh[r]), 0.f);
      }
      *(h4*)(outh + (size_t)pxg * 64 + o0) = o4;
    }
  } else {
    float fm = (1.f - Aatt[(size_t)b * HW + hwpx]) * Batt[(size_t)b * HW + hwpx];
    #pragma unroll
    for (int mt = 0; mt < MT; mt++) {
      int o0 = mt * 16 + lg * 4;
      f4 sc = *(const f4*)(scale + o0);
      f4 sh = *(const f4*)(shift + o0);
      #pragma unroll
      for (int r = 0; r < 4; r++) {
        float v = fmaxf(fmaf(acc[mt][r], sc[r], sh[r]), 0.f) * fm;
        outf[((size_t)b * 32 + o0 + r) * HW + hwpx] = v;
      }
    }
  }
}

} // namespace

extern "C" void kernel_launch(void* const* d_in, const int* in_sizes, int n_in,
                              void* d_out, int out_size, void* d_ws, size_t ws_size,
                              hipStream_t stream) {
  const float* pA   = (const float*)d_in[1];
  const float* pB   = (const float*)d_in[2];
  const float* Aatt = (const float*)d_in[3];
  const float* Batt = (const float*)d_in[4];
  const float* wo1  = (const float*)d_in[5];
  const float* bo1  = (const float*)d_in[6];
  const float* w1   = (const float*)d_in[7];
  const float* g1   = (const float*)d_in[8];
  const float* be1  = (const float*)d_in[9];
  const float* rm1  = (const float*)d_in[10];
  const float* rv1  = (const float*)d_in[11];
  const float* wo2  = (const float*)d_in[12];
  const float* bo2  = (const float*)d_in[13];
  const float* w2   = (const float*)d_in[14];
  const float* g2   = (const float*)d_in[15];
  const float* be2  = (const float*)d_in[16];
  const float* rm2  = (const float*)d_in[17];
  const float* rv2  = (const float*)d_in[18];

  float* ws = (float*)d_ws;
  float*     off   = ws + OFF_OFF;
  _Float16*  xh1   = (_Float16*)(ws + XH1_OFF);
  _Float16*  out1h = (_Float16*)(ws + OUT1_OFF);
  _Float16*  wA1   = (_Float16*)(ws + WA1_OFF);
  _Float16*  wA2   = (_Float16*)(ws + WA2_OFF);
  _Float16*  wO1   = (_Float16*)(ws + WO1_OFF);
  _Float16*  wO2   = (_Float16*)(ws + WO2_OFF);
  float*     bn    = ws + BN_OFF;
  float* sc1 = bn;       float* sh1 = bn + 64;
  float* sc2 = bn + 128; float* sh2 = bn + 160;
  float* bO1 = bn + 192; float* bO2 = bn + 224;

  prep_kernel<<<(PREP_N + 255) / 256, 256, 0, stream>>>(
      w1, w2, wo1, wo2, g1, be1, rm1, rv1, g2, be2, rm2, rv2,
      bo1, bo2, wA1, wA2, wO1, wO2, bn);

  xcat_kernel<<<1024, 256, 0, stream>>>(pA, pB, xh1);

  // stage 1
  convoff_kernel<<<1024, 256, 0, stream>>>(xh1, wO1, bO1, off);
  deform_kernel<64, false><<<1024, 256, 0, stream>>>(
      xh1, off, wA1, sc1, sh1, nullptr, nullptr, out1h, nullptr);

  // stage 2
  convoff_kernel<<<1024, 256, 0, stream>>>(out1h, wO2, bO2, off);
  deform_kernel<32, true><<<1024, 256, 0, stream>>>(
      out1h, off, wA2, sc2, sh2, Aatt, Batt, nullptr, (float*)d_out);
}